// Round 4
// baseline (520.931 us; speedup 1.0000x reference)
//
#include <hip/hip_runtime.h>
#include <hip/hip_bf16.h>
#include <math.h>

#define B_ 256
#define T_ 256
#define I_ 2048
#define H_ 128

#define NSLICE 256   // 8 chunks * 32 K-slices (K=64 each)
#define NITER  288   // 256 GEMM slices + 32-step scan lag

typedef __attribute__((ext_vector_type(8))) short bf16x8;
typedef __attribute__((ext_vector_type(4))) float f32x4;

static __device__ inline short f2bf(float f) {
    __hip_bfloat16 h = __float2bfloat16(f);
    return *reinterpret_cast<short*>(&h);
}

// ---------------------------------------------------------------------------
// Pre-kernel: W_ih fp32 [128][2048] -> bf16 (L2-resident operand for fused).
// 262144 elts / 8 per thread = 32768 threads = 128 blocks.
// ---------------------------------------------------------------------------
__global__ __launch_bounds__(256) void convW(
    const float* __restrict__ W, short* __restrict__ Wb)
{
    const int g = blockIdx.x * 256 + threadIdx.x;
    const float4 v0 = reinterpret_cast<const float4*>(W)[2 * g];
    const float4 v1 = reinterpret_cast<const float4*>(W)[2 * g + 1];
    bf16x8 o;
    o[0] = f2bf(v0.x); o[1] = f2bf(v0.y); o[2] = f2bf(v0.z); o[3] = f2bf(v0.w);
    o[4] = f2bf(v1.x); o[5] = f2bf(v1.y); o[6] = f2bf(v1.z); o[7] = f2bf(v1.w);
    reinterpret_cast<bf16x8*>(Wb)[g] = o;
}

// ---------------------------------------------------------------------------
// Fused kernel: one block per batch row. 384 threads = 6 waves.
//   waves 0-1 (tid<128): GEMM producer. Wave mw owns m-tile mw (16 timesteps
//     of the 32-step chunk) x all 128 cols. Per iteration: one K=64 slice
//     (2 k-tiles of 16x16x32 MFMA, 16 MFMA/wave). A-frags straight from
//     global x (fp32->bf16, 1-slice reg prefetch); B-frags straight from
//     L2-hot bf16 W_ih. Finished chunk (+bias) -> xp_lds[chunk&1].
//   waves 2-5 (tid>=128): scan consumer. Step t=it-32: thread (j,g) holds
//     W_hh[j][64g..+63] in VGPRs, h broadcast via LDS, halves combined with
//     shfl_xor(32), tanh via exp, h double-buffered. One barrier/iteration.
// ---------------------------------------------------------------------------
__global__ __launch_bounds__(384, 1) void fused_kernel(
    const float* __restrict__ x, const short* __restrict__ Wb,
    const float* __restrict__ bih, const float* __restrict__ bhh,
    const float* __restrict__ Whh, const float* __restrict__ Wfc,
    const float* __restrict__ bfc, float* __restrict__ out)
{
    __shared__ __align__(16) float xp_lds[2][32][H_];  // 32 KB chunk dbuf
    __shared__ __align__(16) float hbuf[2][H_];

    const int tid = threadIdx.x;
    const int b   = blockIdx.x;

    // ----- GEMM thread decode (tid < 128) -----
    const int lane = tid & 63;
    const int fr   = lane & 15;      // A: timestep-in-tile / B: col-in-tile
    const int fq   = lane >> 4;      // k-chunk *8
    const int mw   = (tid >> 6) & 1; // wave -> m-tile

    f32x4 acc[8];
    float biasr[8];
    const float* xlane = nullptr;
    const short* wlane = nullptr;

    // ----- scan thread decode (tid >= 128) -----
    const int stid  = tid - 128;
    const int sw    = stid >> 6;
    const int slane = stid & 63;
    const int j     = sw * 32 + (slane & 31);
    const int g     = slane >> 5;
    float Wreg[64];

    if (tid < 128) {
        #pragma unroll
        for (int n = 0; n < 8; ++n) acc[n] = (f32x4){0.f, 0.f, 0.f, 0.f};
        #pragma unroll
        for (int n = 0; n < 8; ++n) {
            const int col = n * 16 + fr;
            biasr[n] = bih[col] + bhh[col];
        }
        xlane = x + ((long)b * T_ + mw * 16 + fr) * I_ + fq * 8;
        wlane = Wb + fr * I_ + fq * 8;
    } else {
        const float4* wp = reinterpret_cast<const float4*>(&Whh[(long)j * H_ + g * 64]);
        #pragma unroll
        for (int q = 0; q < 16; ++q) {
            const float4 wv = wp[q];
            Wreg[4*q]   = wv.x; Wreg[4*q+1] = wv.y;
            Wreg[4*q+2] = wv.z; Wreg[4*q+3] = wv.w;
        }
        if (stid < H_) hbuf[0][stid] = 0.f;
    }

    // prologue: slice 0 -> bankA
    float4 bankA[4], bankB[4];
    if (tid < 128) {
        #pragma unroll
        for (int kt = 0; kt < 2; ++kt) {
            bankA[2*kt]   = *reinterpret_cast<const float4*>(xlane + kt * 32);
            bankA[2*kt+1] = *reinterpret_cast<const float4*>(xlane + kt * 32 + 4);
        }
    }
    __syncthreads();

    auto step = [&](int it, float4* cur, float4* nxt) {
        if (tid < 128) {
            if (it < NSLICE) {
                // issue next slice's x loads (HBM, ~1 iteration of latency hiding)
                if (it + 1 < NSLICE) {
                    const int s1 = it + 1;
                    const float* p = xlane + (long)(s1 >> 5) * 32 * I_ + (s1 & 31) * 64;
                    #pragma unroll
                    for (int kt = 0; kt < 2; ++kt) {
                        nxt[2*kt]   = *reinterpret_cast<const float4*>(p + kt * 32);
                        nxt[2*kt+1] = *reinterpret_cast<const float4*>(p + kt * 32 + 4);
                    }
                }
                // current slice fp32 regs -> bf16 A-frags
                bf16x8 afrag[2];
                #pragma unroll
                for (int kt = 0; kt < 2; ++kt) {
                    bf16x8 a;
                    a[0] = f2bf(cur[2*kt].x);   a[1] = f2bf(cur[2*kt].y);
                    a[2] = f2bf(cur[2*kt].z);   a[3] = f2bf(cur[2*kt].w);
                    a[4] = f2bf(cur[2*kt+1].x); a[5] = f2bf(cur[2*kt+1].y);
                    a[6] = f2bf(cur[2*kt+1].z); a[7] = f2bf(cur[2*kt+1].w);
                    afrag[kt] = a;
                }
                // B-frags direct from L2-hot bf16 W_ih
                const short* wq = wlane + (it & 31) * 64;
                bf16x8 bfrag[8][2];
                #pragma unroll
                for (int n = 0; n < 8; ++n)
                    #pragma unroll
                    for (int kt = 0; kt < 2; ++kt)
                        bfrag[n][kt] = *reinterpret_cast<const bf16x8*>(
                            wq + n * 16 * I_ + kt * 32);
                #pragma unroll
                for (int n = 0; n < 8; ++n) {
                    acc[n] = __builtin_amdgcn_mfma_f32_16x16x32_bf16(
                        afrag[0], bfrag[n][0], acc[n], 0, 0, 0);
                    acc[n] = __builtin_amdgcn_mfma_f32_16x16x32_bf16(
                        afrag[1], bfrag[n][1], acc[n], 0, 0, 0);
                }
                // end of chunk: dump acc (+bias) to LDS, reset
                if ((it & 31) == 31) {
                    const int qb = (it >> 5) & 1;
                    #pragma unroll
                    for (int n = 0; n < 8; ++n) {
                        #pragma unroll
                        for (int i = 0; i < 4; ++i)
                            xp_lds[qb][mw * 16 + fq * 4 + i][n * 16 + fr] =
                                acc[n][i] + biasr[n];
                        acc[n] = (f32x4){0.f, 0.f, 0.f, 0.f};
                    }
                }
            }
        } else {
            if (it >= 32) {
                const int t  = it - 32;
                const int qb = (t >> 5) & 1;
                const float xpv = xp_lds[qb][t & 31][j];
                const float4* h4 = reinterpret_cast<const float4*>(&hbuf[t & 1][g * 64]);
                float a0 = 0.f, a1 = 0.f, a2 = 0.f, a3 = 0.f;
                #pragma unroll
                for (int q2 = 0; q2 < 16; ++q2) {
                    const float4 hh = h4[q2];   // uniform-per-half-wave broadcast
                    a0 += hh.x * Wreg[4*q2];
                    a1 += hh.y * Wreg[4*q2+1];
                    a2 += hh.z * Wreg[4*q2+2];
                    a3 += hh.w * Wreg[4*q2+3];
                }
                float part = (a0 + a1) + (a2 + a3);
                part += __shfl_xor(part, 32);   // combine k-halves in-wave
                const float pre = part + xpv;
                const float e = __expf(2.f * pre);
                hbuf[(t + 1) & 1][j] = 1.f - 2.f / (e + 1.f);
            }
        }
        __syncthreads();   // one barrier per iteration, all 6 waves
    };

    for (int it = 0; it < NITER; it += 2) {
        step(it,     bankA, bankB);
        step(it + 1, bankB, bankA);
    }

    // final FC: h_T is in hbuf[0] (t=255 wrote (255+1)&1 = 0)
    if (tid >= 128 && stid < 64) {
        float v = hbuf[0][stid] * Wfc[stid] + hbuf[0][stid + 64] * Wfc[stid + 64];
        #pragma unroll
        for (int off = 32; off > 0; off >>= 1) v += __shfl_down(v, off);
        if (stid == 0) out[b] = v + bfc[0];
    }
}

// ---------------------------------------------------------------------------
extern "C" void kernel_launch(void* const* d_in, const int* in_sizes, int n_in,
                              void* d_out, int out_size, void* d_ws, size_t ws_size,
                              hipStream_t stream)
{
    const float* x   = (const float*)d_in[0];
    const float* Wih = (const float*)d_in[1];
    const float* Whh = (const float*)d_in[2];
    const float* bih = (const float*)d_in[3];
    const float* bhh = (const float*)d_in[4];
    const float* Wfc = (const float*)d_in[5];
    const float* bfc = (const float*)d_in[6];
    float* out = (float*)d_out;
    short* Wb  = (short*)d_ws;   // 0.5 MB bf16 copy of W_ih

    convW<<<dim3((H_ * I_) / (256 * 8)), dim3(256), 0, stream>>>(Wih, Wb);
    fused_kernel<<<dim3(B_), dim3(384), 0, stream>>>(
        x, Wb, bih, bhh, Whh, Wfc, bfc, out);
}

// Round 5
// 271.050 us; speedup vs baseline: 1.9219x; 1.9219x over previous
//
#include <hip/hip_runtime.h>
#include <hip/hip_bf16.h>
#include <math.h>

#define B_ 256
#define T_ 256
#define I_ 2048
#define H_ 128

#define BM 128
#define BK 32
#define NKT (I_ / BK)   // 64 K-tiles

typedef __attribute__((ext_vector_type(8))) short bf16x8;
typedef __attribute__((ext_vector_type(4))) float f32x4;

static __device__ inline short f2bf(float f) {
    __hip_bfloat16 h = __float2bfloat16(f);
    return *reinterpret_cast<short*>(&h);
}

static __device__ inline bf16x8 pack8(float4 a, float4 b) {
    bf16x8 r;
    r[0] = f2bf(a.x); r[1] = f2bf(a.y); r[2] = f2bf(a.z); r[3] = f2bf(a.w);
    r[4] = f2bf(b.x); r[5] = f2bf(b.y); r[6] = f2bf(b.z); r[7] = f2bf(b.w);
    return r;
}

// ---------------------------------------------------------------------------
// Kernel 1 (bf16 MFMA, global_load_lds staging):
//   xp[bt][j] = sum_i x[bt][i]*W_ih[j][i] + (b_ih+b_hh)[j]
// Tile 128x128, BK=32, 4 waves (2x2 of 64x64), 16x16x32 bf16 MFMA.
// fp32 tiles staged DIRECTLY to LDS via global_load_lds width=16 (no VGPR
// round trip), double-buffered, ONE barrier per K-step. fp32->bf16 happens
// at frag build. LDS rows are 128 B (32 fp32): XOR-swizzle 16B units
// (both-sides rule: pre-swizzled global source + same XOR on ds_read).
// ---------------------------------------------------------------------------
__global__ __launch_bounds__(256, 2) void proj_mfma(
    const float* __restrict__ x, const float* __restrict__ Wih,
    const float* __restrict__ bih, const float* __restrict__ bhh,
    float* __restrict__ xp)
{
    __shared__ __align__(16) float As[2][BM * BK];   // 2 x 16 KB
    __shared__ __align__(16) float Bs[2][H_ * BK];   // 2 x 16 KB

    const int tid  = threadIdx.x;
    const int lane = tid & 63;
    const int wid  = tid >> 6;
    const int wr   = wid >> 1;      // M half (0/1)
    const int wc   = wid & 1;       // N half (0/1)
    const long row0 = (long)blockIdx.x * BM;

    // staging decode: instruction writes 8 rows x 128 B linearly; lane l ->
    // row (l>>3), slot (l&7). Source unit pre-swizzled so slot u of row r
    // holds global unit u^(r&7).
    const int srow  = lane >> 3;              // row within 8-row chunk
    const int sunit = (lane & 7) ^ srow;      // swizzled global 16B unit

    f32x4 acc[4][4];
    #pragma unroll
    for (int m = 0; m < 4; ++m)
        #pragma unroll
        for (int n = 0; n < 4; ++n)
            acc[m][n] = (f32x4){0.f, 0.f, 0.f, 0.f};

    const int fr = lane & 15;
    const int fq = lane >> 4;

    // per-wave staging bases (4 chunks of 8 rows per matrix)
    const int rb0 = wid * 32;

    // prologue: stage tile 0 into buf 0
    #pragma unroll
    for (int i = 0; i < 4; ++i) {
        const int rbase = rb0 + i * 8;
        const float* ga = x   + (row0 + rbase + srow) * I_ + sunit * 4;
        const float* gb = Wih + (long)(rbase + srow) * I_ + sunit * 4;
        __builtin_amdgcn_global_load_lds(
            (const __attribute__((address_space(1))) void*)ga,
            (__attribute__((address_space(3))) void*)&As[0][rbase * BK], 16, 0, 0);
        __builtin_amdgcn_global_load_lds(
            (const __attribute__((address_space(1))) void*)gb,
            (__attribute__((address_space(3))) void*)&Bs[0][rbase * BK], 16, 0, 0);
    }
    __syncthreads();

    int p = 0;
    for (int t = 0; t < NKT; ++t) {
        // issue next tile's staging into buf p^1 (in flight during compute)
        if (t + 1 < NKT) {
            const int kk = (t + 1) * BK;
            #pragma unroll
            for (int i = 0; i < 4; ++i) {
                const int rbase = rb0 + i * 8;
                const float* ga = x   + (row0 + rbase + srow) * I_ + kk + sunit * 4;
                const float* gb = Wih + (long)(rbase + srow) * I_ + kk + sunit * 4;
                __builtin_amdgcn_global_load_lds(
                    (const __attribute__((address_space(1))) void*)ga,
                    (__attribute__((address_space(3))) void*)&As[p ^ 1][rbase * BK], 16, 0, 0);
                __builtin_amdgcn_global_load_lds(
                    (const __attribute__((address_space(1))) void*)gb,
                    (__attribute__((address_space(3))) void*)&Bs[p ^ 1][rbase * BK], 16, 0, 0);
            }
        }
        // frag build from buf p (swizzled read, fp32 -> bf16) + MFMA
        bf16x8 af[4], bfr[4];
        #pragma unroll
        for (int f = 0; f < 4; ++f) {
            const int ra_ = wr * 64 + f * 16 + fr;
            const float4 a0 = *reinterpret_cast<const float4*>(
                &As[p][ra_ * BK + (((fq * 2)     ^ (ra_ & 7)) * 4)]);
            const float4 a1 = *reinterpret_cast<const float4*>(
                &As[p][ra_ * BK + (((fq * 2 + 1) ^ (ra_ & 7)) * 4)]);
            af[f] = pack8(a0, a1);
            const int rb_ = wc * 64 + f * 16 + fr;
            const float4 b0 = *reinterpret_cast<const float4*>(
                &Bs[p][rb_ * BK + (((fq * 2)     ^ (rb_ & 7)) * 4)]);
            const float4 b1 = *reinterpret_cast<const float4*>(
                &Bs[p][rb_ * BK + (((fq * 2 + 1) ^ (rb_ & 7)) * 4)]);
            bfr[f] = pack8(b0, b1);
        }
        #pragma unroll
        for (int m = 0; m < 4; ++m)
            #pragma unroll
            for (int n = 0; n < 4; ++n)
                acc[m][n] = __builtin_amdgcn_mfma_f32_16x16x32_bf16(
                    af[m], bfr[n], acc[m][n], 0, 0, 0);
        __syncthreads();   // buf p reads done; buf p^1 staging drained
        p ^= 1;
    }

    // epilogue: bias + store (C layout: row=(lane>>4)*4+j, col=lane&15)
    #pragma unroll
    for (int n = 0; n < 4; ++n) {
        const int col = wc * 64 + n * 16 + fr;
        const float bn = bih[col] + bhh[col];
        #pragma unroll
        for (int m = 0; m < 4; ++m) {
            const long rbase = row0 + wr * 64 + m * 16 + fq * 4;
            #pragma unroll
            for (int j = 0; j < 4; ++j)
                xp[(rbase + j) * H_ + col] = acc[m][n][j] + bn;
        }
    }
}

// ---------------------------------------------------------------------------
// Kernel 2 (unchanged from R3): per-batch-row recurrence
// h = tanh(xp_t + h @ W_hh^T); one block per row, 4 waves, W_hh in VGPRs,
// shfl_xor(32) k-half combine, h double-buffered, 1 barrier/step,
// xp prefetched 4 steps ahead.
// ---------------------------------------------------------------------------
__global__ __launch_bounds__(256) void scan_kernel(
    const float* __restrict__ xp, const float* __restrict__ Whh,
    const float* __restrict__ Wfc, const float* __restrict__ bfc,
    float* __restrict__ out)
{
    __shared__ __align__(16) float hbuf[2][H_];

    const int tid  = threadIdx.x;
    const int lane = tid & 63;
    const int w    = tid >> 6;
    const int j    = w * 32 + (lane & 31);
    const int g    = lane >> 5;
    const int b    = blockIdx.x;

    float Wreg[64];
    {
        const float4* wp = reinterpret_cast<const float4*>(&Whh[(long)j * H_ + g * 64]);
        #pragma unroll
        for (int q = 0; q < 16; ++q) {
            const float4 wv = wp[q];
            Wreg[4*q]   = wv.x; Wreg[4*q+1] = wv.y;
            Wreg[4*q+2] = wv.z; Wreg[4*q+3] = wv.w;
        }
    }
    if (tid < H_) hbuf[0][tid] = 0.f;

    const float* xprow = xp + (long)b * T_ * H_ + j;
    float xa = xprow[0 * H_];
    float xb = xprow[1 * H_];
    float xc = xprow[2 * H_];
    float xd = xprow[3 * H_];
    __syncthreads();

    auto body = [&](int t, float xpv) {
        const float4* h4 = reinterpret_cast<const float4*>(&hbuf[t & 1][g * 64]);
        float a0 = 0.f, a1 = 0.f, a2 = 0.f, a3 = 0.f;
        #pragma unroll
        for (int q = 0; q < 16; ++q) {
            const float4 hh = h4[q];
            a0 += hh.x * Wreg[4*q];
            a1 += hh.y * Wreg[4*q+1];
            a2 += hh.z * Wreg[4*q+2];
            a3 += hh.w * Wreg[4*q+3];
        }
        float part = (a0 + a1) + (a2 + a3);
        part += __shfl_xor(part, 32);
        const float pre = part + xpv;
        const float e = __expf(2.f * pre);
        hbuf[(t + 1) & 1][j] = 1.f - 2.f / (e + 1.f);
        __syncthreads();
    };

    for (int t = 0; t < T_; t += 4) {
        float xu;
        xu = xa; if (t + 4 < T_) xa = xprow[(long)(t + 4) * H_];
        body(t + 0, xu);
        xu = xb; if (t + 5 < T_) xb = xprow[(long)(t + 5) * H_];
        body(t + 1, xu);
        xu = xc; if (t + 6 < T_) xc = xprow[(long)(t + 6) * H_];
        body(t + 2, xu);
        xu = xd; if (t + 7 < T_) xd = xprow[(long)(t + 7) * H_];
        body(t + 3, xu);
    }

    if (w == 0) {
        float v = hbuf[0][lane] * Wfc[lane] + hbuf[0][lane + 64] * Wfc[lane + 64];
        #pragma unroll
        for (int off = 32; off > 0; off >>= 1) v += __shfl_down(v, off);
        if (lane == 0) out[b] = v + bfc[0];
    }
}

// ---------------------------------------------------------------------------
extern "C" void kernel_launch(void* const* d_in, const int* in_sizes, int n_in,
                              void* d_out, int out_size, void* d_ws, size_t ws_size,
                              hipStream_t stream)
{
    const float* x   = (const float*)d_in[0];
    const float* Wih = (const float*)d_in[1];
    const float* Whh = (const float*)d_in[2];
    const float* bih = (const float*)d_in[3];
    const float* bhh = (const float*)d_in[4];
    const float* Wfc = (const float*)d_in[5];
    const float* bfc = (const float*)d_in[6];
    float* out = (float*)d_out;
    float* xp  = (float*)d_ws;   // 65536 * 128 floats = 32 MB scratch

    proj_mfma<<<dim3((B_ * T_) / BM), dim3(256), 0, stream>>>(x, Wih, bih, bhh, xp);
    scan_kernel<<<dim3(B_), dim3(256), 0, stream>>>(xp, Whh, Wfc, bfc, out);
}